// Round 6
// baseline (954.381 us; speedup 1.0000x reference)
//
#include <hip/hip_runtime.h>
#include <hip/hip_bf16.h>

typedef float f32x4 __attribute__((ext_vector_type(4)));
typedef __bf16 bf16x8 __attribute__((ext_vector_type(8)));

#define DEV __device__ __forceinline__

constexpr int B_ = 8, S_ = 512, D_ = 512, H_ = 8, L_ = 4, DFF_ = 2048, NI_ = 20000, AD_ = 128, DK_ = 64;
constexpr int N_ = B_ * S_;            // 4096 tokens
constexpr int NOUT_PAD = 20096;        // 157 * 128

DEV void gload_lds16(const void* g, void* l) {
  __builtin_amdgcn_global_load_lds((const __attribute__((address_space(1))) unsigned int*)g,
                                   (__attribute__((address_space(3))) unsigned int*)l, 16, 0, 0);
}

template<int N> DEV void waitv() {
  if constexpr (N == 0)      asm volatile("s_waitcnt vmcnt(0)" ::: "memory");
  else if constexpr (N == 3) asm volatile("s_waitcnt vmcnt(3)" ::: "memory");
  else if constexpr (N == 4) asm volatile("s_waitcnt vmcnt(4)" ::: "memory");
  else if constexpr (N == 6) asm volatile("s_waitcnt vmcnt(6)" ::: "memory");
  else if constexpr (N == 8) asm volatile("s_waitcnt vmcnt(8)" ::: "memory");
}

// m204 bijective XCD-chunk swizzle
DEV int xcd_swizzle(int bid, int nwg) {
  int q = nwg >> 3, r = nwg & 7;
  int x = bid & 7, idx = bid >> 3;
  int base = (x < r) ? x * (q + 1) : r * (q + 1) + (x - r) * q;
  return base + idx;
}

// ---------------------------------------------------------------------------
// Pipelined bf16 GEMM:  C(M x Ncols) = act(A(M x K) * B(N x K)^T + bias)
// 4 waves (2x2), per-wave (BM/2)x(BN/2). BK=32. T4 counted-vmcnt pipeline:
// 4 LDS K-tile buffers, prefetch distance 3, per-iter
//   s_waitcnt vmcnt(2*LT) ; raw s_barrier ; stage(t+3) ; ds_read(t) ; MFMA(t)
// Loads for tiles t+1,t+2 stay in flight ACROSS the barrier (never drained).
// Safety: buffer (t+3)&3 was last read at iter t-1, and all waves' tile t-1
// ds_read data is consumed before they reach barrier t (lgkmcnt waits precede
// the MFMAs), so the stage can never overwrite live data.
// ---------------------------------------------------------------------------
template<int BM, int BN, int OUT_BF16, int ACT, int NT>
__global__ __launch_bounds__(256)
void gemm_p(const __hip_bfloat16* __restrict__ A, int lda, long aS1, long aS2,
            const __hip_bfloat16* __restrict__ Bm, int ldb, long bS1, long bS2,
            void* __restrict__ Cv, int ldc, long cS1, long cS2,
            const float* __restrict__ bias, long biasS2,
            int K, int Ncols, int bdiv)
{
  constexpr int BK = 32, NB = 4;
  constexpr int MI = BM / 32, NJ = BN / 32;
  constexpr int LT = BM / 64 + BN / 64;       // gload_lds instrs per thread per tile
  __shared__ __align__(16) unsigned short smA[NB][BM * BK];
  __shared__ __align__(16) unsigned short smB[NB][BN * BK];

  const int z = blockIdx.z;
  const long za = (long)(z / bdiv) * aS1 + (long)(z % bdiv) * aS2;
  const long zb = (long)(z / bdiv) * bS1 + (long)(z % bdiv) * bS2;
  const long zc = (long)(z / bdiv) * cS1 + (long)(z % bdiv) * cS2;
  const __hip_bfloat16* Ab = A + za;
  const __hip_bfloat16* Bp = Bm + zb;
  const float* bp = bias ? bias + (long)(z % bdiv) * biasS2 : nullptr;

  const int nwg = gridDim.x * gridDim.y;
  const int bid = blockIdx.y * gridDim.x + blockIdx.x;
  const int wgid = xcd_swizzle(bid, nwg);
  const int m0 = (wgid % gridDim.x) * BM, n0 = (wgid / gridDim.x) * BN;

  const int tid = threadIdx.x, wv = tid >> 6, lane = tid & 63;
  const int l15 = lane & 15, l4 = lane >> 4;
  const int wm = (wv >> 1) * (BM / 2), wn = (wv & 1) * (BN / 2);

  auto stage = [&](int buf, int k0) {
#pragma unroll
    for (int it = 0; it < BM / 64; ++it) {
      int c = it * 256 + tid;                  // chunk of 8 bf16
      int row = c >> 2, cc = c & 3;
      gload_lds16((const void*)(Ab + (size_t)(m0 + row) * lda + k0 + cc * 8),
                  (void*)&smA[buf][(size_t)(it * 256 + wv * 64) * 8]);
    }
#pragma unroll
    for (int it = 0; it < BN / 64; ++it) {
      int c = it * 256 + tid;
      int row = c >> 2, cc = c & 3;
      gload_lds16((const void*)(Bp + (size_t)(n0 + row) * ldb + k0 + cc * 8),
                  (void*)&smB[buf][(size_t)(it * 256 + wv * 64) * 8]);
    }
  };

  f32x4 acc[MI][NJ];
#pragma unroll
  for (int i = 0; i < MI; ++i)
#pragma unroll
    for (int j = 0; j < NJ; ++j) acc[i][j] = f32x4{0.f, 0.f, 0.f, 0.f};

  const int nk = K / BK;                       // >= 4 for all call sites
  stage(0, 0);
  stage(1, BK);
  stage(2, 2 * BK);

  for (int t = 0; t < nk; ++t) {
    if (t + 2 < nk)      waitv<2 * LT>();      // tile t landed; t+1,t+2 in flight
    else if (t + 1 < nk) waitv<LT>();
    else                 waitv<0>();
    __builtin_amdgcn_s_barrier();              // raw: no vmcnt(0) drain
    __builtin_amdgcn_sched_barrier(0);

    if (t + 3 < nk) stage((t + 3) & 3, (t + 3) * BK);   // prefetch issue (async)

    const int cur = t & 3;
    bf16x8 af[MI], bfr[NJ];
#pragma unroll
    for (int i = 0; i < MI; ++i)
      af[i] = *reinterpret_cast<const bf16x8*>(&smA[cur][(wm + i * 16 + l15) * BK + l4 * 8]);
#pragma unroll
    for (int j = 0; j < NJ; ++j)
      bfr[j] = *reinterpret_cast<const bf16x8*>(&smB[cur][(wn + j * 16 + l15) * BK + l4 * 8]);
    __builtin_amdgcn_s_setprio(1);
#pragma unroll
    for (int i = 0; i < MI; ++i)
#pragma unroll
      for (int j = 0; j < NJ; ++j)
        acc[i][j] = __builtin_amdgcn_mfma_f32_16x16x32_bf16(af[i], bfr[j], acc[i][j], 0, 0, 0);
    __builtin_amdgcn_s_setprio(0);
  }

  // epilogue: C/D layout col = lane&15, row = (lane>>4)*4 + r  [m89/m91 verified]
#pragma unroll
  for (int i = 0; i < MI; ++i) {
#pragma unroll
    for (int j = 0; j < NJ; ++j) {
#pragma unroll
      for (int r = 0; r < 4; ++r) {
        int row = m0 + wm + i * 16 + l4 * 4 + r;
        int col = n0 + wn + j * 16 + l15;
        if (col < Ncols) {
          float v = acc[i][j][r];
          if (bp) v += bp[col];
          if (ACT == 1) v = v > 0.f ? v : 0.f;
          if constexpr (OUT_BF16) {
            ((__hip_bfloat16*)Cv)[zc + (size_t)row * ldc + col] = __float2bfloat16(v);
          } else {
            float* dst = &((float*)Cv)[zc + (size_t)row * ldc + col];
            if constexpr (NT) __builtin_nontemporal_store(v, dst);
            else *dst = v;
          }
        }
      }
    }
  }
}

// ---------------------------------------------------------------------------
// Fused flash attention (verified round 5). One block = one (b,h) x 64 q-rows.
// ---------------------------------------------------------------------------
__global__ __launch_bounds__(256)
void k_flash(const __hip_bfloat16* __restrict__ q, const __hip_bfloat16* __restrict__ k,
             const __hip_bfloat16* __restrict__ vt, const float* __restrict__ mask,
             __hip_bfloat16* __restrict__ ctx)
{
  __shared__ __align__(16) unsigned short Ql[64 * 64];
  __shared__ __align__(16) unsigned short Kl[2][64 * 64];
  __shared__ __align__(16) unsigned short Vl[2][64 * 64];
  __shared__ __align__(16) unsigned short Pl[4][16 * 64];

  const int qt = blockIdx.x, bh = blockIdx.y;
  const int b = bh >> 3, h = bh & 7;
  const int tid = threadIdx.x, wv = tid >> 6, lane = tid & 63;
  const int l15 = lane & 15, l4 = lane >> 4;
  const int q0 = qt * 64;

  const __hip_bfloat16* Qg = q + ((size_t)(b * 512 + q0) * 512) + h * 64;
  const __hip_bfloat16* Kg = k + ((size_t)(b * 512) * 512) + h * 64;
  const __hip_bfloat16* Vg = vt + ((size_t)bh * 64) * 512;
  const float* mk = mask + b * 512;

  auto stageQ = [&]() {
#pragma unroll
    for (int it = 0; it < 2; ++it) {
      int idx = it * 256 + wv * 64 + lane;
      int row = idx >> 3, c = idx & 7;
      gload_lds16((const void*)(Qg + (size_t)row * 512 + (c ^ (row & 7)) * 8),
                  (void*)&Ql[(it * 256 + wv * 64) * 8]);
    }
  };
  auto stageKV = [&](int buf, int kv0) {
#pragma unroll
    for (int it = 0; it < 2; ++it) {
      int idx = it * 256 + wv * 64 + lane;
      int row = idx >> 3, c = idx & 7;
      gload_lds16((const void*)(Kg + (size_t)(kv0 + row) * 512 + (c ^ (row & 7)) * 8),
                  (void*)&Kl[buf][(it * 256 + wv * 64) * 8]);
    }
#pragma unroll
    for (int it = 0; it < 2; ++it) {
      int idx = it * 256 + wv * 64 + lane;
      int row = idx >> 3, c = idx & 7;
      gload_lds16((const void*)(Vg + (size_t)row * 512 + kv0 + (c ^ (row & 7)) * 8),
                  (void*)&Vl[buf][(it * 256 + wv * 64) * 8]);
    }
  };

  stageQ();
  stageKV(0, 0);
  __syncthreads();

  bf16x8 aq[2];
#pragma unroll
  for (int kk = 0; kk < 2; ++kk) {
    int row = wv * 16 + l15;
    aq[kk] = *reinterpret_cast<const bf16x8*>(
        &Ql[row * 64 + (((kk * 4 + l4) ^ (row & 7)) * 8)]);
  }

  f32x4 accO[4];
  float mrun[4], lrun[4];
#pragma unroll
  for (int j = 0; j < 4; ++j) accO[j] = f32x4{0.f, 0.f, 0.f, 0.f};
#pragma unroll
  for (int r = 0; r < 4; ++r) { mrun[r] = -3e38f; lrun[r] = 0.f; }

  int cur = 0;
  for (int t = 0; t < 8; ++t) {
    if (t + 1 < 8) stageKV(cur ^ 1, (t + 1) * 64);
    const int kv0 = t * 64;

    f32x4 s[4];
#pragma unroll
    for (int j = 0; j < 4; ++j) s[j] = f32x4{0.f, 0.f, 0.f, 0.f};
#pragma unroll
    for (int kk = 0; kk < 2; ++kk) {
#pragma unroll
      for (int j = 0; j < 4; ++j) {
        int row = j * 16 + l15;
        bf16x8 bk = *reinterpret_cast<const bf16x8*>(
            &Kl[cur][row * 64 + (((kk * 4 + l4) ^ (row & 7)) * 8)]);
        s[j] = __builtin_amdgcn_mfma_f32_16x16x32_bf16(aq[kk], bk, s[j], 0, 0, 0);
      }
    }

#pragma unroll
    for (int j = 0; j < 4; ++j) {
      float mval = mk[kv0 + j * 16 + l15];
#pragma unroll
      for (int r = 0; r < 4; ++r)
        s[j][r] = (mval == 0.f) ? -1e30f : s[j][r];
    }

    float alpha[4];
#pragma unroll
    for (int r = 0; r < 4; ++r) {
      float v = fmaxf(fmaxf(s[0][r], s[1][r]), fmaxf(s[2][r], s[3][r]));
      v = fmaxf(v, __shfl_xor(v, 1));
      v = fmaxf(v, __shfl_xor(v, 2));
      v = fmaxf(v, __shfl_xor(v, 4));
      v = fmaxf(v, __shfl_xor(v, 8));
      float mn = fmaxf(mrun[r], v);
      alpha[r] = __expf(mrun[r] - mn);
      mrun[r] = mn;
    }
    float rs[4] = {0.f, 0.f, 0.f, 0.f};
#pragma unroll
    for (int j = 0; j < 4; ++j)
#pragma unroll
      for (int r = 0; r < 4; ++r) {
        float p = __expf(s[j][r] - mrun[r]);
        s[j][r] = p;
        rs[r] += p;
      }
#pragma unroll
    for (int r = 0; r < 4; ++r) {
      float v = rs[r];
      v += __shfl_xor(v, 1); v += __shfl_xor(v, 2);
      v += __shfl_xor(v, 4); v += __shfl_xor(v, 8);
      lrun[r] = lrun[r] * alpha[r] + v;
#pragma unroll
      for (int j = 0; j < 4; ++j) accO[j][r] *= alpha[r];
    }

#pragma unroll
    for (int j = 0; j < 4; ++j)
#pragma unroll
      for (int r = 0; r < 4; ++r) {
        int qrow = l4 * 4 + r, key = j * 16 + l15;
        __hip_bfloat16 hb = __float2bfloat16(s[j][r]);
        Pl[wv][qrow * 64 + (((key >> 3) ^ (qrow & 7)) * 8) + (key & 7)] =
            *reinterpret_cast<unsigned short*>(&hb);
      }

#pragma unroll
    for (int kc = 0; kc < 2; ++kc) {
      bf16x8 ap = *reinterpret_cast<const bf16x8*>(
          &Pl[wv][l15 * 64 + (((kc * 4 + l4) ^ (l15 & 7)) * 8)]);
#pragma unroll
      for (int j = 0; j < 4; ++j) {
        int row = j * 16 + l15;
        bf16x8 bv2 = *reinterpret_cast<const bf16x8*>(
            &Vl[cur][row * 64 + (((kc * 4 + l4) ^ (row & 7)) * 8)]);
        accO[j] = __builtin_amdgcn_mfma_f32_16x16x32_bf16(ap, bv2, accO[j], 0, 0, 0);
      }
    }
    __syncthreads();
    cur ^= 1;
  }

#pragma unroll
  for (int r = 0; r < 4; ++r) {
    float inv = lrun[r] > 0.f ? 1.f / lrun[r] : 0.f;
#pragma unroll
    for (int j = 0; j < 4; ++j) {
      int row = q0 + wv * 16 + l4 * 4 + r;
      int col = h * 64 + j * 16 + l15;
      ctx[(size_t)(b * 512 + row) * 512 + col] = __float2bfloat16(accO[j][r] * inv);
    }
  }
}

// ---------------------------------------------------------------------------
__global__ void k_transpose(const float* __restrict__ in, __hip_bfloat16* __restrict__ out,
                            int K, int N, long inBatch, long outBatch, float scale)
{
  __shared__ float tile[32][33];
  int z = blockIdx.z;
  const float* ip = in + (long)z * inBatch;
  __hip_bfloat16* op = out + (long)z * outBatch;
  int n0 = blockIdx.x * 32, k0 = blockIdx.y * 32;
  int tx = threadIdx.x, ty = threadIdx.y;
#pragma unroll
  for (int r = 0; r < 4; ++r) {
    int k = k0 + ty + r * 8, n = n0 + tx;
    if (k < K && n < N) tile[ty + r * 8][tx] = ip[(size_t)k * N + n];
  }
  __syncthreads();
#pragma unroll
  for (int r = 0; r < 4; ++r) {
    int n = n0 + ty + r * 8, k = k0 + tx;
    if (n < N && k < K) op[(size_t)n * K + k] = __float2bfloat16(tile[tx][ty + r * 8] * scale);
  }
}

__global__ void k_cvt(const float* __restrict__ in, __hip_bfloat16* __restrict__ out) {
  int i = blockIdx.x * 256 + threadIdx.x;
  out[i] = __float2bfloat16(in[i]);
}

__global__ void k_packbias(const float* __restrict__ bq, const float* __restrict__ bk,
                           const float* __restrict__ bv, float* __restrict__ out) {
  int i = blockIdx.x * 256 + threadIdx.x;   // L*3*512
  int d = i & 511, t = (i >> 9) % 3, l = i / (3 * 512);
  const float* src = (t == 0) ? bq : (t == 1) ? bk : bv;
  out[i] = src[l * 512 + d] * (t == 0 ? 0.125f : 1.f);
}

__global__ void k_gather(const int* __restrict__ ids, const float* __restrict__ tbl,
                         __hip_bfloat16* __restrict__ cat) {
  int n = blockIdx.x, t = threadIdx.x;
  int id = ids[n];
  const float* src = tbl + (size_t)id * 512;
  size_t dst = (size_t)n * 1024;
  float a0 = (id == 0) ? 0.f : src[t];
  float a1 = (id == 0) ? 0.f : src[t + 256];
  cat[dst + t] = __float2bfloat16(a0);
  cat[dst + t + 256] = __float2bfloat16(a1);
}

__global__ void k_peadd(float* __restrict__ xf, __hip_bfloat16* __restrict__ xb,
                        const float* __restrict__ pe) {
  int i = blockIdx.x * 256 + threadIdx.x;
  float v = xf[i] + pe[i & (S_ * D_ - 1)];
  xf[i] = v;
  xb[i] = __float2bfloat16(v);
}

__global__ void k_vtrans(const __hip_bfloat16* __restrict__ v, __hip_bfloat16* __restrict__ vt) {
  int i = blockIdx.x * 256 + threadIdx.x;          // B*H*DK*S
  int s = i & 511, d = (i >> 9) & 63, h = (i >> 15) & 7, b = i >> 18;
  vt[i] = v[(size_t)((b << 9) + s) * 512 + (h << 6) + d];
}

__global__ void k_ln(const float* __restrict__ x, const float* __restrict__ y,
                     const float* __restrict__ gam, const float* __restrict__ bet,
                     float* __restrict__ xout, __hip_bfloat16* __restrict__ xb) {
  int row = blockIdx.x, t = threadIdx.x;
  size_t base = (size_t)row * 512;
  float v0 = x[base + t], v1 = x[base + t + 256];
  if (y) { v0 += y[base + t]; v1 += y[base + t + 256]; }
  __shared__ float sm[4];
  float s = v0 + v1;
  for (int o = 32; o; o >>= 1) s += __shfl_xor(s, o);
  if ((t & 63) == 0) sm[t >> 6] = s;
  __syncthreads();
  float mean = (sm[0] + sm[1] + sm[2] + sm[3]) * (1.f / 512.f);
  __syncthreads();
  float d0 = v0 - mean, d1 = v1 - mean;
  float qq = d0 * d0 + d1 * d1;
  for (int o = 32; o; o >>= 1) qq += __shfl_xor(qq, o);
  if ((t & 63) == 0) sm[t >> 6] = qq;
  __syncthreads();
  float var = (sm[0] + sm[1] + sm[2] + sm[3]) * (1.f / 512.f);
  float rs = rsqrtf(var + 1e-5f);
  float o0 = d0 * rs * gam[t] + bet[t];
  float o1 = d1 * rs * gam[t + 256] + bet[t + 256];
  xout[base + t] = o0;
  xout[base + t + 256] = o1;
  xb[base + t] = __float2bfloat16(o0);
  xb[base + t + 256] = __float2bfloat16(o1);
}

__global__ void k_gate(const float* __restrict__ xn, const float* __restrict__ g,
                       const float* __restrict__ org, const float* __restrict__ wgl,
                       __hip_bfloat16* __restrict__ xg) {
  int i = blockIdx.x * 256 + threadIdx.x;
  float zz = g[i] + org[i >> 9] * wgl[i & 511];
  float sg = 1.f / (1.f + expf(-zz));
  xg[i] = __float2bfloat16(xn[i] * sg);
}

// ---------------------------------------------------------------------------
extern "C" void kernel_launch(void* const* d_in, const int* in_sizes, int n_in,
                              void* d_out, int out_size, void* d_ws, size_t ws_size,
                              hipStream_t stream) {
  typedef __hip_bfloat16 bf;
  const int*   item_ids = (const int*)  d_in[0];
  const float* audio    = (const float*)d_in[1];
  const float* organic  = (const float*)d_in[2];
  const float* mask     = (const float*)d_in[3];
  const float* emb      = (const float*)d_in[4];
  const float* pe       = (const float*)d_in[5];
  const float* Wa1 = (const float*)d_in[6],  *ba1 = (const float*)d_in[7];
  const float* Wa2 = (const float*)d_in[8],  *ba2 = (const float*)d_in[9];
  const float* Wf  = (const float*)d_in[10], *bfb = (const float*)d_in[11];
  const float* Wq  = (const float*)d_in[12], *bq  = (const float*)d_in[13];
  const float* Wk  = (const float*)d_in[14], *bk  = (const float*)d_in[15];
  const float* Wv  = (const float*)d_in[16], *bv  = (const float*)d_in[17];
  const float* Wo  = (const float*)d_in[18], *bo  = (const float*)d_in[19];
  const float* ln1s = (const float*)d_in[22], *ln1b = (const float*)d_in[23];
  const float* ln2s = (const float*)d_in[24], *ln2b = (const float*)d_in[25];
  const float* Wff1 = (const float*)d_in[26], *bff1 = (const float*)d_in[27];
  const float* Wff2 = (const float*)d_in[28], *bff2 = (const float*)d_in[29];
  const float* lnOs = (const float*)d_in[30], *lnOb = (const float*)d_in[31];
  const float* Wg   = (const float*)d_in[32], *bg   = (const float*)d_in[33];
  const float* Wout = (const float*)d_in[34], *bout = (const float*)d_in[35];
  float* out = (float*)d_out;

  char* ws = (char*)d_ws;
  size_t off = 0;
  auto alloc = [&](size_t bytes) -> char* {
    char* p = ws + off;
    off = (off + bytes + 255) & ~(size_t)255;
    return p;
  };
  bf* Wa1T = (bf*)alloc((size_t)512 * 128 * 2);
  bf* Wa2T = (bf*)alloc((size_t)512 * 512 * 2);
  bf* WfT  = (bf*)alloc((size_t)512 * 1024 * 2);
  bf* WqkvT = (bf*)alloc((size_t)L_ * 3 * D_ * D_ * 2);   // [L][3][D][D]
  bf* WoT  = (bf*)alloc((size_t)L_ * D_ * D_ * 2);
  bf* Wff1T = (bf*)alloc((size_t)L_ * DFF_ * D_ * 2);
  bf* Wff2T = (bf*)alloc((size_t)L_ * D_ * DFF_ * 2);
  bf* WgT   = (bf*)alloc((size_t)512 * 512 * 2);
  bf* WoutT = (bf*)alloc((size_t)NOUT_PAD * 512 * 2);
  float* bqkv = (float*)alloc((size_t)L_ * 3 * 512 * 4);
  bf* ab    = (bf*)alloc((size_t)N_ * AD_ * 2);
  bf* cat   = (bf*)alloc((size_t)N_ * 1024 * 2);
  bf* ah    = (bf*)alloc((size_t)N_ * 512 * 2);
  float* xf = (float*)alloc((size_t)N_ * 512 * 4);
  bf* xb    = (bf*)alloc((size_t)N_ * 512 * 2);
  bf* qkv   = (bf*)alloc((size_t)3 * N_ * 512 * 2);       // [3][N][D]
  bf* vt    = (bf*)alloc((size_t)B_ * H_ * DK_ * S_ * 2);
  bf* ctxb  = (bf*)alloc((size_t)N_ * 512 * 2);
  float* ybuf = (float*)alloc((size_t)N_ * 512 * 4);
  bf* ff1b  = (bf*)alloc((size_t)N_ * DFF_ * 2);
  bf* xg    = (bf*)alloc((size_t)N_ * 512 * 2);
  if (off > ws_size) return;  // loud failure (output stays poisoned)

  bf* qb = qkv;
  bf* kb = qkv + (size_t)N_ * 512;
  bf* vb = qkv + (size_t)2 * N_ * 512;

  dim3 tb(32, 8);
  // weight transposes -> bf16, K-major (Wq scaled by 1/8: attention scale folded)
  k_transpose<<<dim3(16, 4, 1),  tb, 0, stream>>>(Wa1, Wa1T, 128, 512, 0, 0, 1.f);
  k_transpose<<<dim3(16, 16, 1), tb, 0, stream>>>(Wa2, Wa2T, 512, 512, 0, 0, 1.f);
  k_transpose<<<dim3(16, 32, 1), tb, 0, stream>>>(Wf, WfT, 1024, 512, 0, 0, 1.f);
  k_transpose<<<dim3(16, 16, L_), tb, 0, stream>>>(Wq, WqkvT, 512, 512,
      (long)D_ * D_, (long)3 * D_ * D_, 0.125f);
  k_transpose<<<dim3(16, 16, L_), tb, 0, stream>>>(Wk, WqkvT + (size_t)D_ * D_, 512, 512,
      (long)D_ * D_, (long)3 * D_ * D_, 1.f);
  k_transpose<<<dim3(16, 16, L_), tb, 0, stream>>>(Wv, WqkvT + (size_t)2 * D_ * D_, 512, 512,
      (long)D_ * D_, (long)3 * D_ * D_, 1.f);
  k_transpose<<<dim3(16, 16, L_), tb, 0, stream>>>(Wo, WoT, 512, 512, (long)D_ * D_, (long)D_ * D_, 1.f);
  k_transpose<<<dim3(64, 16, L_), tb, 0, stream>>>(Wff1, Wff1T, 512, 2048, (long)D_ * DFF_, (long)D_ * DFF_, 1.f);
  k_transpose<<<dim3(16, 64, L_), tb, 0, stream>>>(Wff2, Wff2T, 2048, 512, (long)DFF_ * D_, (long)DFF_ * D_, 1.f);
  k_transpose<<<dim3(16, 16, 1), tb, 0, stream>>>(Wg, WgT, 512, 512, 0, 0, 1.f);
  k_transpose<<<dim3(625, 16, 1), tb, 0, stream>>>(Wout, WoutT, 512, 20000, 0, 0, 1.f);
  k_packbias<<<(L_ * 3 * 512) / 256, 256, 0, stream>>>(bq, bk, bv, bqkv);

  // front-end
  k_cvt<<<(N_ * AD_) / 256, 256, 0, stream>>>(audio, ab);
  k_gather<<<N_, 256, 0, stream>>>(item_ids, emb, cat);
  gemm_p<128, 64, 1, 1, 0><<<dim3(32, 8, 1), 256, 0, stream>>>(ab, 128, 0, 0, Wa1T, 128, 0, 0,
      (void*)ah, 512, 0, 0, ba1, 0, 128, 512, 1);
  gemm_p<128, 64, 1, 0, 0><<<dim3(32, 8, 1), 256, 0, stream>>>(ah, 512, 0, 0, Wa2T, 512, 0, 0,
      (void*)(cat + 512), 1024, 0, 0, ba2, 0, 512, 512, 1);
  gemm_p<128, 64, 0, 1, 0><<<dim3(32, 8, 1), 256, 0, stream>>>(cat, 1024, 0, 0, WfT, 1024, 0, 0,
      (void*)xf, 512, 0, 0, bfb, 0, 1024, 512, 1);
  k_peadd<<<(N_ * D_) / 256, 256, 0, stream>>>(xf, xb, pe);

  // layers
  for (int l = 0; l < L_; ++l) {
    gemm_p<128, 64, 1, 0, 0><<<dim3(32, 8, 3), 256, 0, stream>>>(xb, 512, 0, 0,
        WqkvT + (size_t)l * 3 * D_ * D_, 512, 0, (long)D_ * D_,
        (void*)qkv, 512, 0, (long)N_ * D_,
        bqkv + (size_t)l * 3 * 512, 512, 512, 512, 3);
    k_vtrans<<<(B_ * H_ * DK_ * S_) / 256, 256, 0, stream>>>(vb, vt);
    k_flash<<<dim3(8, B_ * H_), 256, 0, stream>>>(qb, kb, vt, mask, ctxb);
    gemm_p<128, 64, 0, 0, 0><<<dim3(32, 8, 1), 256, 0, stream>>>(ctxb, 512, 0, 0,
        WoT + (size_t)l * D_ * D_, 512, 0, 0, (void*)ybuf, 512, 0, 0, bo + l * D_, 0, 512, 512, 1);
    k_ln<<<N_, 256, 0, stream>>>(xf, ybuf, ln1s + l * D_, ln1b + l * D_, xf, xb);
    gemm_p<128, 128, 1, 1, 0><<<dim3(32, 16, 1), 256, 0, stream>>>(xb, 512, 0, 0,
        Wff1T + (size_t)l * DFF_ * D_, 512, 0, 0, (void*)ff1b, 2048, 0, 0, bff1 + l * DFF_, 0, 512, 2048, 1);
    gemm_p<128, 64, 0, 0, 0><<<dim3(32, 8, 1), 256, 0, stream>>>(ff1b, 2048, 0, 0,
        Wff2T + (size_t)l * D_ * DFF_, 2048, 0, 0, (void*)ybuf, 512, 0, 0, bff2 + l * D_, 0, 2048, 512, 1);
    k_ln<<<N_, 256, 0, stream>>>(xf, ybuf, ln2s + l * D_, ln2b + l * D_, xf, xb);
  }

  // final LN + gate + logits
  k_ln<<<N_, 256, 0, stream>>>(xf, nullptr, lnOs, lnOb, xf, xb);
  gemm_p<128, 64, 0, 0, 0><<<dim3(32, 8, 1), 256, 0, stream>>>(xb, 512, 0, 0, WgT, 512, 0, 0,
      (void*)ybuf, 512, 0, 0, bg, 0, 512, 512, 1);
  k_gate<<<(N_ * D_) / 256, 256, 0, stream>>>(xf, ybuf, organic, Wg + (size_t)512 * 512, xg);
  // logits: 4096x20000x512 -> 128x128 pipelined tile, NT streaming f32 stores
  gemm_p<128, 128, 0, 0, 1><<<dim3(32, 157, 1), 256, 0, stream>>>(xg, 512, 0, 0, WoutT, 512, 0, 0,
      (void*)out, 20000, 0, 0, bout, 0, 512, 20000, 1);
}

// Round 7
// 926.226 us; speedup vs baseline: 1.0304x; 1.0304x over previous
//
#include <hip/hip_runtime.h>
#include <hip/hip_bf16.h>

typedef float f32x4 __attribute__((ext_vector_type(4)));
typedef __bf16 bf16x8 __attribute__((ext_vector_type(8)));

#define DEV __device__ __forceinline__

constexpr int B_ = 8, S_ = 512, D_ = 512, H_ = 8, L_ = 4, DFF_ = 2048, NI_ = 20000, AD_ = 128, DK_ = 64;
constexpr int N_ = B_ * S_;            // 4096 tokens
constexpr int NOUT_PAD = 20224;        // 79 * 256 (gemm8 tile multiple)

DEV void gload_lds16(const void* g, void* l) {
  __builtin_amdgcn_global_load_lds((const __attribute__((address_space(1))) unsigned int*)g,
                                   (__attribute__((address_space(3))) unsigned int*)l, 16, 0, 0);
}

template<int N> DEV void waitv() {
  if constexpr (N == 0)      asm volatile("s_waitcnt vmcnt(0)" ::: "memory");
  else if constexpr (N == 2) asm volatile("s_waitcnt vmcnt(2)" ::: "memory");
  else if constexpr (N == 4) asm volatile("s_waitcnt vmcnt(4)" ::: "memory");
}
DEV void barx() { asm volatile("s_barrier" ::: "memory"); }  // raw barrier, no drain; memory clobber pins compiler ordering

// m204 bijective XCD-chunk swizzle
DEV int xcd_swizzle(int bid, int nwg) {
  int q = nwg >> 3, r = nwg & 7;
  int x = bid & 7, idx = bid >> 3;
  int base = (x < r) ? x * (q + 1) : r * (q + 1) + (x - r) * q;
  return base + idx;
}

// ---------------------------------------------------------------------------
// 8-phase 256x256 GEMM (T2+T3+T4+T5), BK=64, 8 waves (2M x 4N), 512 threads.
// C = act(A(M x K) * B(N x K)^T + bias). LDS = ring of k-half slots
// [2 buf][2 ksl][256 rows][32 cols] per matrix (128 KB). Per K-tile: 4 phases
// of 16 MFMA; each phase stages ONE k-half of K-tile kt+1 (2 global_load_lds)
// and ds-reads one register subtile. Counted vmcnt(2)/vmcnt(4) at phase 1/4
// ends only -- loads stay in flight across barriers. LDS involution
// chunk ^= (row ^ row>>2)&3 applied to BOTH the global source and the ds_read
// (rule #21) -> 2-way bank conflicts (free).
// Hazards (all proven): stage at kt.phP targets a slot whose last reader
// phase ended >= one barrier before the stager's current position.
// ---------------------------------------------------------------------------
template<int OUT_BF16, int ACT, int NT>
__global__ __launch_bounds__(512)
void gemm8(const __hip_bfloat16* __restrict__ A, int lda,
           const __hip_bfloat16* __restrict__ Bm, int ldb,
           void* __restrict__ Cv, int ldc,
           const float* __restrict__ bias, int K, int Ncols)
{
  __shared__ __align__(16) unsigned short As[2][2][256 * 32];
  __shared__ __align__(16) unsigned short Bs[2][2][256 * 32];

  const int nwg = gridDim.x * gridDim.y;
  const int bid = blockIdx.y * gridDim.x + blockIdx.x;
  const int wgid = xcd_swizzle(bid, nwg);
  const int m0 = (wgid % gridDim.x) * 256, n0 = (wgid / gridDim.x) * 256;

  const int tid = threadIdx.x, wv = tid >> 6, lane = tid & 63;
  const int l15 = lane & 15, l4 = lane >> 4;
  const int wr = wv >> 2, wc = wv & 3;       // wave grid 2(M) x 4(N)

  auto stageA = [&](int buf, int kh, int kt) {
#pragma unroll
    for (int i2 = 0; i2 < 2; ++i2) {
      int g = i2 * 512 + tid, rho = g >> 2, c = g & 3;
      int sc = c ^ ((rho ^ (rho >> 2)) & 3);
      gload_lds16((const void*)(A + (size_t)(m0 + rho) * lda + kt * 64 + kh * 32 + sc * 8),
                  (void*)&As[buf][kh][(size_t)(i2 * 512 + wv * 64) * 8]);
    }
  };
  auto stageB = [&](int buf, int kh, int kt) {
#pragma unroll
    for (int i2 = 0; i2 < 2; ++i2) {
      int g = i2 * 512 + tid, rho = g >> 2, c = g & 3;
      int sc = c ^ ((rho ^ (rho >> 2)) & 3);
      gload_lds16((const void*)(Bm + (size_t)(n0 + rho) * ldb + kt * 64 + kh * 32 + sc * 8),
                  (void*)&Bs[buf][kh][(size_t)(i2 * 512 + wv * 64) * 8]);
    }
  };
  auto rdA = [&](int buf, int ks, int i) -> bf16x8 {
    int row = wr * 128 + i * 16 + l15;
    int c = l4 ^ ((row ^ (row >> 2)) & 3);
    return *reinterpret_cast<const bf16x8*>(&As[buf][ks][row * 32 + c * 8]);
  };
  auto rdB = [&](int buf, int ks, int j) -> bf16x8 {
    int row = wc * 64 + j * 16 + l15;
    int c = l4 ^ ((row ^ (row >> 2)) & 3);
    return *reinterpret_cast<const bf16x8*>(&Bs[buf][ks][row * 32 + c * 8]);
  };

  f32x4 acc[8][4];
#pragma unroll
  for (int i = 0; i < 8; ++i)
#pragma unroll
    for (int j = 0; j < 4; ++j) acc[i][j] = f32x4{0.f, 0.f, 0.f, 0.f};

  const int nk = K / 64;
  // prologue: K-tile 0 fully staged, one-time full drain
  stageA(0, 0, 0); stageB(0, 0, 0); stageA(0, 1, 0); stageB(0, 1, 0);
  __syncthreads();

  for (int kt = 0; kt < nk; ++kt) {
    const int buf = kt & 1, nb = buf ^ 1;
    const bool pf = (kt + 1 < nk);
    bf16x8 bh0[4], bh1[4], at[4];

    // ---- phase 1: (m0-3, k-slice0); stage A-kh0 of kt+1
#pragma unroll
    for (int i = 0; i < 4; ++i) at[i] = rdA(buf, 0, i);
#pragma unroll
    for (int j = 0; j < 4; ++j) bh0[j] = rdB(buf, 0, j);
    if (pf) stageA(nb, 0, kt + 1);
    __builtin_amdgcn_s_setprio(1);
#pragma unroll
    for (int i = 0; i < 4; ++i)
#pragma unroll
      for (int j = 0; j < 4; ++j)
        acc[i][j] = __builtin_amdgcn_mfma_f32_16x16x32_bf16(at[i], bh0[j], acc[i][j], 0, 0, 0);
    __builtin_amdgcn_s_setprio(0);
    waitv<2>();                 // kt-1.ph3/ph4 stages (this K-tile's ph2 data) landed
    barx();

    // ---- phase 2: (m0-3, k-slice1); stage B-kh0 of kt+1
#pragma unroll
    for (int i = 0; i < 4; ++i) at[i] = rdA(buf, 1, i);
#pragma unroll
    for (int j = 0; j < 4; ++j) bh1[j] = rdB(buf, 1, j);
    if (pf) stageB(nb, 0, kt + 1);
    __builtin_amdgcn_s_setprio(1);
#pragma unroll
    for (int i = 0; i < 4; ++i)
#pragma unroll
      for (int j = 0; j < 4; ++j)
        acc[i][j] = __builtin_amdgcn_mfma_f32_16x16x32_bf16(at[i], bh1[j], acc[i][j], 0, 0, 0);
    __builtin_amdgcn_s_setprio(0);
    barx();

    // ---- phase 3: (m4-7, k-slice0); stage A-kh1 of kt+1 (B ks0 frags reused from regs)
#pragma unroll
    for (int i = 0; i < 4; ++i) at[i] = rdA(buf, 0, i + 4);
    if (pf) stageA(nb, 1, kt + 1);
    __builtin_amdgcn_s_setprio(1);
#pragma unroll
    for (int i = 0; i < 4; ++i)
#pragma unroll
      for (int j = 0; j < 4; ++j)
        acc[i + 4][j] = __builtin_amdgcn_mfma_f32_16x16x32_bf16(at[i], bh0[j], acc[i + 4][j], 0, 0, 0);
    __builtin_amdgcn_s_setprio(0);
    barx();

    // ---- phase 4: (m4-7, k-slice1); stage B-kh1 of kt+1
#pragma unroll
    for (int i = 0; i < 4; ++i) at[i] = rdA(buf, 1, i + 4);
    if (pf) stageB(nb, 1, kt + 1);
    __builtin_amdgcn_s_setprio(1);
#pragma unroll
    for (int i = 0; i < 4; ++i)
#pragma unroll
      for (int j = 0; j < 4; ++j)
        acc[i + 4][j] = __builtin_amdgcn_mfma_f32_16x16x32_bf16(at[i], bh1[j], acc[i + 4][j], 0, 0, 0);
    __builtin_amdgcn_s_setprio(0);
    waitv<4>();                 // kt.ph1/ph2 stages (next K-tile's ph1 data) landed
    barx();
  }

  // epilogue: C/D layout col = lane&15, row = (lane>>4)*4 + r
#pragma unroll
  for (int i = 0; i < 8; ++i) {
#pragma unroll
    for (int j = 0; j < 4; ++j) {
#pragma unroll
      for (int r = 0; r < 4; ++r) {
        int row = m0 + wr * 128 + i * 16 + l4 * 4 + r;
        int col = n0 + wc * 64 + j * 16 + l15;
        if (col < Ncols) {
          float v = acc[i][j][r];
          if (bias) v += bias[col];
          if (ACT == 1) v = v > 0.f ? v : 0.f;
          if constexpr (OUT_BF16) {
            ((__hip_bfloat16*)Cv)[(size_t)row * ldc + col] = __float2bfloat16(v);
          } else {
            float* dst = &((float*)Cv)[(size_t)row * ldc + col];
            if constexpr (NT) __builtin_nontemporal_store(v, dst);
            else *dst = v;
          }
        }
      }
    }
  }
}

// ---------------------------------------------------------------------------
// 2-phase bf16 GEMM (verified rounds 3-5) for small/medium shapes.
// ---------------------------------------------------------------------------
template<int BM, int BN, int OUT_BF16, int ACT, int NT>
__global__ __launch_bounds__(BM * 2)
void gemm_bt(const __hip_bfloat16* __restrict__ A, int lda, long aS1, long aS2,
             const __hip_bfloat16* __restrict__ Bm, int ldb, long bS1, long bS2,
             void* __restrict__ Cv, int ldc, long cS1, long cS2,
             const float* __restrict__ bias, long biasS2,
             int K, int Ncols, int bdiv)
{
  constexpr int BK = 32;
  constexpr int NW = BM / 32;
  constexpr int WTN = BN / 2, NJ = WTN / 16;
  __shared__ __align__(16) unsigned short smA[2][BM * BK];
  __shared__ __align__(16) unsigned short smB[2][BN * BK];

  const int z = blockIdx.z;
  const long za = (long)(z / bdiv) * aS1 + (long)(z % bdiv) * aS2;
  const long zb = (long)(z / bdiv) * bS1 + (long)(z % bdiv) * bS2;
  const long zc = (long)(z / bdiv) * cS1 + (long)(z % bdiv) * cS2;
  const __hip_bfloat16* Ab = A + za;
  const __hip_bfloat16* Bp = Bm + zb;
  const float* bp = bias ? bias + (long)(z % bdiv) * biasS2 : nullptr;

  const int nwg = gridDim.x * gridDim.y;
  const int bid = blockIdx.y * gridDim.x + blockIdx.x;
  const int wgid = xcd_swizzle(bid, nwg);
  const int m0 = (wgid % gridDim.x) * BM, n0 = (wgid / gridDim.x) * BN;

  const int tid = threadIdx.x, wv = tid >> 6, lane = tid & 63;
  const int l15 = lane & 15, l4 = lane >> 4;
  const int wm = (wv >> 1) * 64, wn = (wv & 1) * WTN;

  auto stage = [&](int buf, int k0) {
#pragma unroll
    for (int it = 0; it < BM / 16 / NW; ++it) {
      int c = (it * NW + wv) * 64 + lane;
      int row = c >> 2, cc = c & 3;
      gload_lds16((const void*)(Ab + (size_t)(m0 + row) * lda + k0 + cc * 8),
                  (void*)&smA[buf][(size_t)(it * NW + wv) * 512]);
    }
#pragma unroll
    for (int it = 0; it < BN / 16 / NW; ++it) {
      int c = (it * NW + wv) * 64 + lane;
      int row = c >> 2, cc = c & 3;
      gload_lds16((const void*)(Bp + (size_t)(n0 + row) * ldb + k0 + cc * 8),
                  (void*)&smB[buf][(size_t)(it * NW + wv) * 512]);
    }
  };

  f32x4 acc[4][NJ];
#pragma unroll
  for (int i = 0; i < 4; ++i)
#pragma unroll
    for (int j = 0; j < NJ; ++j) acc[i][j] = f32x4{0.f, 0.f, 0.f, 0.f};

  const int nk = K / BK;
  stage(0, 0);
  __syncthreads();

  int cur = 0;
  for (int t = 0; t < nk; ++t) {
    if (t + 1 < nk) stage(cur ^ 1, (t + 1) * BK);

    bf16x8 af[4], bfr[NJ];
#pragma unroll
    for (int i = 0; i < 4; ++i)
      af[i] = *reinterpret_cast<const bf16x8*>(&smA[cur][(wm + i * 16 + l15) * BK + l4 * 8]);
#pragma unroll
    for (int j = 0; j < NJ; ++j)
      bfr[j] = *reinterpret_cast<const bf16x8*>(&smB[cur][(wn + j * 16 + l15) * BK + l4 * 8]);
    __builtin_amdgcn_s_setprio(1);
#pragma unroll
    for (int i = 0; i < 4; ++i)
#pragma unroll
      for (int j = 0; j < NJ; ++j)
        acc[i][j] = __builtin_amdgcn_mfma_f32_16x16x32_bf16(af[i], bfr[j], acc[i][j], 0, 0, 0);
    __builtin_amdgcn_s_setprio(0);
    __syncthreads();
    cur ^= 1;
  }

#pragma unroll
  for (int i = 0; i < 4; ++i) {
#pragma unroll
    for (int j = 0; j < NJ; ++j) {
#pragma unroll
      for (int r = 0; r < 4; ++r) {
        int row = m0 + wm + i * 16 + l4 * 4 + r;
        int col = n0 + wn + j * 16 + l15;
        if (col < Ncols) {
          float v = acc[i][j][r];
          if (bp) v += bp[col];
          if (ACT == 1) v = v > 0.f ? v : 0.f;
          if constexpr (OUT_BF16) {
            ((__hip_bfloat16*)Cv)[zc + (size_t)row * ldc + col] = __float2bfloat16(v);
          } else {
            float* dst = &((float*)Cv)[zc + (size_t)row * ldc + col];
            if constexpr (NT) __builtin_nontemporal_store(v, dst);
            else *dst = v;
          }
        }
      }
    }
  }
}

// ---------------------------------------------------------------------------
// Fused flash attention (verified round 5).
// ---------------------------------------------------------------------------
__global__ __launch_bounds__(256)
void k_flash(const __hip_bfloat16* __restrict__ q, const __hip_bfloat16* __restrict__ k,
             const __hip_bfloat16* __restrict__ vt, const float* __restrict__ mask,
             __hip_bfloat16* __restrict__ ctx)
{
  __shared__ __align__(16) unsigned short Ql[64 * 64];
  __shared__ __align__(16) unsigned short Kl[2][64 * 64];
  __shared__ __align__(16) unsigned short Vl[2][64 * 64];
  __shared__ __align__(16) unsigned short Pl[4][16 * 64];

  const int qt = blockIdx.x, bh = blockIdx.y;
  const int b = bh >> 3, h = bh & 7;
  const int tid = threadIdx.x, wv = tid >> 6, lane = tid & 63;
  const int l15 = lane & 15, l4 = lane >> 4;
  const int q0 = qt * 64;

  const __hip_bfloat16* Qg = q + ((size_t)(b * 512 + q0) * 512) + h * 64;
  const __hip_bfloat16* Kg = k + ((size_t)(b * 512) * 512) + h * 64;
  const __hip_bfloat16* Vg = vt + ((size_t)bh * 64) * 512;
  const float* mk = mask + b * 512;

  auto stageQ = [&]() {
#pragma unroll
    for (int it = 0; it < 2; ++it) {
      int idx = it * 256 + wv * 64 + lane;
      int row = idx >> 3, c = idx & 7;
      gload_lds16((const void*)(Qg + (size_t)row * 512 + (c ^ (row & 7)) * 8),
                  (void*)&Ql[(it * 256 + wv * 64) * 8]);
    }
  };
  auto stageKV = [&](int buf, int kv0) {
#pragma unroll
    for (int it = 0; it < 2; ++it) {
      int idx = it * 256 + wv * 64 + lane;
      int row = idx >> 3, c = idx & 7;
      gload_lds16((const void*)(Kg + (size_t)(kv0 + row) * 512 + (c ^ (row & 7)) * 8),
                  (void*)&Kl[buf][(it * 256 + wv * 64) * 8]);
    }
#pragma unroll
    for (int it = 0; it < 2; ++it) {
      int idx = it * 256 + wv * 64 + lane;
      int row = idx >> 3, c = idx & 7;
      gload_lds16((const void*)(Vg + (size_t)row * 512 + kv0 + (c ^ (row & 7)) * 8),
                  (void*)&Vl[buf][(it * 256 + wv * 64) * 8]);
    }
  };

  stageQ();
  stageKV(0, 0);
  __syncthreads();

  bf16x8 aq[2];
#pragma unroll
  for (int kk = 0; kk < 2; ++kk) {
    int row = wv * 16 + l15;
    aq[kk] = *reinterpret_cast<const bf16x8*>(
        &Ql[row * 64 + (((kk * 4 + l4) ^ (row & 7)) * 8)]);
  }

  f32x4 accO[4];
  float mrun[4], lrun[4];
#pragma unroll
  for (int j = 0; j < 4; ++j) accO[j] = f32x4{0.f, 0.f, 0.f, 0.f};
#pragma unroll
  for (int r = 0; r < 4; ++r) { mrun[r] = -3e38f; lrun[r] = 0.f; }

  int cur = 0;
  for (int t = 0; t < 8; ++t) {
    if (t + 1 < 8) stageKV(cur ^ 1, (t + 1) * 64);
    const int kv0 = t * 64;

    f32x4 s[4];
#pragma unroll
    for (int j = 0; j < 4; ++j) s[j] = f32x4{0.f, 0.f, 0.f, 0.f};
#pragma unroll
    for (int kk = 0; kk < 2; ++kk) {
#pragma unroll
      for (int j = 0; j < 4; ++j) {
        int row = j * 16 + l15;
        bf16x8 bk = *reinterpret_cast<const bf16x8*>(
            &Kl[cur][row * 64 + (((kk * 4 + l4) ^ (row & 7)) * 8)]);
        s[j] = __builtin_amdgcn_mfma_f32_16x16x32_bf16(aq[kk], bk, s[j], 0, 0, 0);
      }
    }

#pragma unroll
    for (int j = 0; j < 4; ++j) {
      float mval = mk[kv0 + j * 16 + l15];
#pragma unroll
      for (int r = 0; r < 4; ++r)
        s[j][r] = (mval == 0.f) ? -1e30f : s[j][r];
    }

    float alpha[4];
#pragma unroll
    for (int r = 0; r < 4; ++r) {
      float v = fmaxf(fmaxf(s[0][r], s[1][r]), fmaxf(s[2][r], s[3][r]));
      v = fmaxf(v, __shfl_xor(v, 1));
      v = fmaxf(v, __shfl_xor(v, 2));
      v = fmaxf(v, __shfl_xor(v, 4));
      v = fmaxf(v, __shfl_xor(v, 8));
      float mn = fmaxf(mrun[r], v);
      alpha[r] = __expf(mrun[r] - mn);
      mrun[r] = mn;
    }
    float rs[4] = {0.f, 0.f, 0.f, 0.f};
#pragma unroll
    for (int j = 0; j < 4; ++j)
#pragma unroll
      for (int r = 0; r < 4; ++r) {
        float p = __expf(s[j][r] - mrun[r]);
        s[j][r] = p;
        rs[r] += p;
      }
#pragma unroll
    for (int r = 0; r < 4; ++r) {
      float v = rs[r];
      v += __shfl_xor(v, 1); v += __shfl_xor(v, 2);
      v += __shfl_xor(v, 4); v += __shfl_xor(v, 8);
      lrun[r] = lrun[r] * alpha[r] + v;
#pragma unroll
      for (int j = 0; j < 4; ++j) accO[j][r] *= alpha[r];
    }

#pragma unroll
    for (int j = 0; j < 4; ++j)
#pragma unroll
      for (int r = 0; r < 4; ++r) {
        int qrow = l4 * 4 + r, key = j * 16 + l15;
        __hip_bfloat16 hb = __float2bfloat16(s[j][r]);
        Pl[wv][qrow * 64 + (((key >> 3) ^ (qrow & 7)) * 8) + (key & 7)] =
            *reinterpret_cast<unsigned short*>(&hb);
      }

#pragma unroll
    for (int kc = 0; kc < 2; ++kc) {
      bf16x8 ap = *reinterpret_cast<const bf16x8*>(
          &Pl[wv][l15 * 64 + (((kc * 4 + l4) ^ (l15 & 7)) * 8)]);
#pragma unroll
      for (int j = 0; j < 4; ++j) {
        int row = j * 16 + l15;
        bf16x8 bv2 = *reinterpret_cast<const bf16x8*>(
            &Vl[cur][row * 64 + (((kc * 4 + l4) ^ (row & 7)) * 8)]);
        accO[j] = __builtin_amdgcn_mfma_f32_16x16x32_bf16(ap, bv2, accO[j], 0, 0, 0);
      }
    }
    __syncthreads();
    cur ^= 1;
  }

#pragma unroll
  for (int r = 0; r < 4; ++r) {
    float inv = lrun[r] > 0.f ? 1.f / lrun[r] : 0.f;
#pragma unroll
    for (int j = 0; j < 4; ++j) {
      int row = q0 + wv * 16 + l4 * 4 + r;
      int col = h * 64 + j * 16 + l15;
      ctx[(size_t)(b * 512 + row) * 512 + col] = __float2bfloat16(accO[j][r] * inv);
    }
  }
}

// ---------------------------------------------------------------------------
__global__ void k_transpose(const float* __restrict__ in, __hip_bfloat16* __restrict__ out,
                            int K, int N, long inBatch, long outBatch, float scale)
{
  __shared__ float tile[32][33];
  int z = blockIdx.z;
  const float* ip = in + (long)z * inBatch;
  __hip_bfloat16* op = out + (long)z * outBatch;
  int n0 = blockIdx.x * 32, k0 = blockIdx.y * 32;
  int tx = threadIdx.x, ty = threadIdx.y;
#pragma unroll
  for (int r = 0; r < 4; ++r) {
    int k = k0 + ty + r * 8, n = n0 + tx;
    if (k < K && n < N) tile[ty + r * 8][tx] = ip[(size_t)k * N + n];
  }
  __syncthreads();
#pragma unroll
  for (int r = 0; r < 4; ++r) {
    int n = n0 + ty + r * 8, k = k0 + tx;
    if (n < N && k < K) op[(size_t)n * K + k] = __float2bfloat16(tile[tx][ty + r * 8] * scale);
  }
}

__global__ void k_cvt(const float* __restrict__ in, __hip_bfloat16* __restrict__ out) {
  int i = blockIdx.x * 256 + threadIdx.x;
  out[i] = __float2bfloat16(in[i]);
}

__global__ void k_packbias(const float* __restrict__ bq, const float* __restrict__ bk,
                           const float* __restrict__ bv, float* __restrict__ out) {
  int i = blockIdx.x * 256 + threadIdx.x;   // L*3*512
  int d = i & 511, t = (i >> 9) % 3, l = i / (3 * 512);
  const float* src = (t == 0) ? bq : (t == 1) ? bk : bv;
  out[i] = src[l * 512 + d] * (t == 0 ? 0.125f : 1.f);
}

__global__ void k_gather(const int* __restrict__ ids, const float* __restrict__ tbl,
                         __hip_bfloat16* __restrict__ cat) {
  int n = blockIdx.x, t = threadIdx.x;
  int id = ids[n];
  const float* src = tbl + (size_t)id * 512;
  size_t dst = (size_t)n * 1024;
  float a0 = (id == 0) ? 0.f : src[t];
  float a1 = (id == 0) ? 0.f : src[t + 256];
  cat[dst + t] = __float2bfloat16(a0);
  cat[dst + t + 256] = __float2bfloat16(a1);
}

__global__ void k_peadd(float* __restrict__ xf, __hip_bfloat16* __restrict__ xb,
                        const float* __restrict__ pe) {
  int i = blockIdx.x * 256 + threadIdx.x;
  float v = xf[i] + pe[i & (S_ * D_ - 1)];
  xf[i] = v;
  xb[i] = __float2bfloat16(v);
}

__global__ void k_vtrans(const __hip_bfloat16* __restrict__ v, __hip_bfloat16* __restrict__ vt) {
  int i = blockIdx.x * 256 + threadIdx.x;          // B*H*DK*S
  int s = i & 511, d = (i >> 9) & 63, h = (i >> 15) & 7, b = i >> 18;
  vt[i] = v[(size_t)((b << 9) + s) * 512 + (h << 6) + d];
}

__global__ void k_ln(const float* __restrict__ x, const float* __restrict__ y,
                     const float* __restrict__ gam, const float* __restrict__ bet,
                     float* __restrict__ xout, __hip_bfloat16* __restrict__ xb) {
  int row = blockIdx.x, t = threadIdx.x;
  size_t base = (size_t)row * 512;
  float v0 = x[base + t], v1 = x[base + t + 256];
  if (y) { v0 += y[base + t]; v1 += y[base + t + 256]; }
  __shared__ float sm[4];
  float s = v0 + v1;
  for (int o = 32; o; o >>= 1) s += __shfl_xor(s, o);
  if ((t & 63) == 0) sm[t >> 6] = s;
  __syncthreads();
  float mean = (sm[0] + sm[1] + sm[2] + sm[3]) * (1.f / 512.f);
  __syncthreads();
  float d0 = v0 - mean, d1 = v1 - mean;
  float qq = d0 * d0 + d1 * d1;
  for (int o = 32; o; o >>= 1) qq += __shfl_xor(qq, o);
  if ((t & 63) == 0) sm[t >> 6] = qq;
  __syncthreads();
  float var = (sm[0] + sm[1] + sm[2] + sm[3]) * (1.f / 512.f);
  float rs = rsqrtf(var + 1e-5f);
  float o0 = d0 * rs * gam[t] + bet[t];
  float o1 = d1 * rs * gam[t + 256] + bet[t + 256];
  xout[base + t] = o0;
  xout[base + t + 256] = o1;
  xb[base + t] = __float2bfloat16(o0);
  xb[base + t + 256] = __float2bfloat16(o1);
}

__global__ void k_gate(const float* __restrict__ xn, const float* __restrict__ g,
                       const float* __restrict__ org, const float* __restrict__ wgl,
                       __hip_bfloat16* __restrict__ xg) {
  int i = blockIdx.x * 256 + threadIdx.x;
  float zz = g[i] + org[i >> 9] * wgl[i & 511];
  float sg = 1.f / (1.f + expf(-zz));
  xg[i] = __float2bfloat16(xn[i] * sg);
}

// ---------------------------------------------------------------------------
extern "C" void kernel_launch(void* const* d_in, const int* in_sizes, int n_in,
                              void* d_out, int out_size, void* d_ws, size_t ws_size,
                              hipStream_t stream) {
  typedef __hip_bfloat16 bf;
  const int*   item_ids = (const int*)  d_in[0];
  const float* audio    = (const float*)d_in[1];
  const float* organic  = (const float*)d_in[2];
  const float* mask     = (const float*)d_in[3];
  const float* emb      = (const float*)d_in[4];
  const float* pe       = (const float*)d_in[5];
  const float* Wa1 = (const float*)d_in[6],  *ba1 = (const float*)d_in[7];
  const float* Wa2 = (const float*)d_in[8],  *ba2 = (const float*)d_in[9];
  const float* Wf  = (const float*)d_in[10], *bfb = (const float*)d_in[11];
  const float* Wq  = (const float*)d_in[12], *bq  = (const float*)d_in[13];
  const float* Wk  = (const float*)d_in[14], *bk  = (const float*)d_in[15];
  const float* Wv  = (const float*)d_in[16], *bv  = (const float*)d_in[17];
  const float* Wo  = (const float*)d_in[18], *bo  = (const float*)d_in[19];
  const float* ln1s = (const float*)d_in[22], *ln1b = (const float*)d_in[23];
  const float* ln2s = (const float*)d_in[24], *ln2b = (const float*)d_in[25];
  const float* Wff1 = (const float*)d_in[26], *bff1 = (const float*)d_in[27];
  const float* Wff2 = (const float*)d_in[28], *bff2 = (const float*)d_in[29];
  const float* lnOs = (const float*)d_in[30], *lnOb = (const float*)d_in[31];
  const float* Wg   = (const float*)d_in[32], *bg   = (const float*)d_in[33];
  const float* Wout = (const float*)d_in[34], *bout = (const float*)d_in[35];
  float* out = (float*)d_out;

  char* ws = (char*)d_ws;
  size_t off = 0;
  auto alloc = [&](size_t bytes) -> char* {
    char* p = ws + off;
    off = (off + bytes + 255) & ~(size_t)255;
    return p;
  };
  bf* Wa1T = (bf*)alloc((size_t)512 * 128 * 2);
  bf* Wa2T = (bf*)alloc((size_t)512 * 512 * 2);
  bf* WfT  = (bf*)alloc((size_t)512 * 1024 * 2);
  bf* WqkvT = (bf*)alloc((size_t)L_ * 3 * D_ * D_ * 2);   // [L][3][D][D]
  bf* WoT  = (bf*)alloc((size_t)L_ * D_ * D_ * 2);
  bf* Wff1T = (bf*)alloc((size_t)L_ * DFF_ * D_ * 2);
  bf* Wff2T = (bf*)alloc((size_t)L_ * D_ * DFF_ * 2);
  bf* WgT   = (bf*)alloc((size_t)512 * 512 * 2);
  bf* WoutT = (bf*)alloc((size_t)NOUT_PAD * 512 * 2);
  float* bqkv = (float*)alloc((size_t)L_ * 3 * 512 * 4);
  bf* ab    = (bf*)alloc((size_t)N_ * AD_ * 2);
  bf* cat   = (bf*)alloc((size_t)N_ * 1024 * 2);
  bf* ah    = (bf*)alloc((size_t)N_ * 512 * 2);
  float* xf = (float*)alloc((size_t)N_ * 512 * 4);
  bf* xb    = (bf*)alloc((size_t)N_ * 512 * 2);
  bf* qkv   = (bf*)alloc((size_t)3 * N_ * 512 * 2);       // [3][N][D]
  bf* vt    = (bf*)alloc((size_t)B_ * H_ * DK_ * S_ * 2);
  bf* ctxb  = (bf*)alloc((size_t)N_ * 512 * 2);
  float* ybuf = (float*)alloc((size_t)N_ * 512 * 4);
  bf* ff1b  = (bf*)alloc((size_t)N_ * DFF_ * 2);
  bf* xg    = (bf*)alloc((size_t)N_ * 512 * 2);
  if (off > ws_size) return;  // loud failure (output stays poisoned)

  bf* qb = qkv;
  bf* kb = qkv + (size_t)N_ * 512;
  bf* vb = qkv + (size_t)2 * N_ * 512;

  dim3 tb(32, 8);
  // weight transposes -> bf16, K-major (Wq scaled by 1/8: attention scale folded)
  k_transpose<<<dim3(16, 4, 1),  tb, 0, stream>>>(Wa1, Wa1T, 128, 512, 0, 0, 1.f);
  k_transpose<<<dim3(16, 16, 1), tb, 0, stream>>>(Wa2, Wa2T, 512, 512, 0, 0, 1.f);
  k_transpose<<<dim3(16, 32, 1), tb, 0, stream>>>(Wf, WfT, 1024, 512, 0, 0, 1.f);
  k_transpose<<<dim3(16, 16, L_), tb, 0, stream>>>(Wq, WqkvT, 512, 512,
      (long)D_ * D_, (long)3 * D_ * D_, 0.125f);
  k_transpose<<<dim3(16, 16, L_), tb, 0, stream>>>(Wk, WqkvT + (size_t)D_ * D_, 512, 512,
      (long)D_ * D_, (long)3 * D_ * D_, 1.f);
  k_transpose<<<dim3(16, 16, L_), tb, 0, stream>>>(Wv, WqkvT + (size_t)2 * D_ * D_, 512, 512,
      (long)D_ * D_, (long)3 * D_ * D_, 1.f);
  k_transpose<<<dim3(16, 16, L_), tb, 0, stream>>>(Wo, WoT, 512, 512, (long)D_ * D_, (long)D_ * D_, 1.f);
  k_transpose<<<dim3(64, 16, L_), tb, 0, stream>>>(Wff1, Wff1T, 512, 2048, (long)D_ * DFF_, (long)D_ * DFF_, 1.f);
  k_transpose<<<dim3(16, 64, L_), tb, 0, stream>>>(Wff2, Wff2T, 2048, 512, (long)DFF_ * D_, (long)DFF_ * D_, 1.f);
  k_transpose<<<dim3(16, 16, 1), tb, 0, stream>>>(Wg, WgT, 512, 512, 0, 0, 1.f);
  k_transpose<<<dim3(625, 16, 1), tb, 0, stream>>>(Wout, WoutT, 512, 20000, 0, 0, 1.f);
  k_packbias<<<(L_ * 3 * 512) / 256, 256, 0, stream>>>(bq, bk, bv, bqkv);

  // front-end
  k_cvt<<<(N_ * AD_) / 256, 256, 0, stream>>>(audio, ab);
  k_gather<<<N_, 256, 0, stream>>>(item_ids, emb, cat);
  gemm_bt<128, 64, 1, 1, 0><<<dim3(32, 8, 1), 256, 0, stream>>>(ab, 128, 0, 0, Wa1T, 128, 0, 0,
      (void*)ah, 512, 0, 0, ba1, 0, 128, 512, 1);
  gemm_bt<128, 64, 1, 0, 0><<<dim3(32, 8, 1), 256, 0, stream>>>(ah, 512, 0, 0, Wa2T, 512, 0, 0,
      (void*)(cat + 512), 1024, 0, 0, ba2, 0, 512, 512, 1);
  gemm_bt<128, 64, 0, 1, 0><<<dim3(32, 8, 1), 256, 0, stream>>>(cat, 1024, 0, 0, WfT, 1024, 0, 0,
      (void*)xf, 512, 0, 0, bfb, 0, 1024, 512, 1);
  k_peadd<<<(N_ * D_) / 256, 256, 0, stream>>>(xf, xb, pe);

  // layers
  for (int l = 0; l < L_; ++l) {
    gemm_bt<128, 64, 1, 0, 0><<<dim3(32, 8, 3), 256, 0, stream>>>(xb, 512, 0, 0,
        WqkvT + (size_t)l * 3 * D_ * D_, 512, 0, (long)D_ * D_,
        (void*)qkv, 512, 0, (long)N_ * D_,
        bqkv + (size_t)l * 3 * 512, 512, 512, 512, 3);
    k_vtrans<<<(B_ * H_ * DK_ * S_) / 256, 256, 0, stream>>>(vb, vt);
    k_flash<<<dim3(8, B_ * H_), 256, 0, stream>>>(qb, kb, vt, mask, ctxb);
    gemm_bt<128, 64, 0, 0, 0><<<dim3(32, 8, 1), 256, 0, stream>>>(ctxb, 512, 0, 0,
        WoT + (size_t)l * D_ * D_, 512, 0, 0, (void*)ybuf, 512, 0, 0, bo + l * D_, 0, 512, 512, 1);
    k_ln<<<N_, 256, 0, stream>>>(xf, ybuf, ln1s + l * D_, ln1b + l * D_, xf, xb);
    // FF1: 4096x2048x512 -> 8-phase 256x256
    gemm8<1, 1, 0><<<dim3(16, 8), 512, 0, stream>>>(xb, 512,
        Wff1T + (size_t)l * DFF_ * D_, 512, (void*)ff1b, 2048, bff1 + l * DFF_, 512, 2048);
    gemm_bt<128, 64, 0, 0, 0><<<dim3(32, 8, 1), 256, 0, stream>>>(ff1b, 2048, 0, 0,
        Wff2T + (size_t)l * D_ * DFF_, 2048, 0, 0, (void*)ybuf, 512, 0, 0, bff2 + l * D_, 0, 2048, 512, 1);
    k_ln<<<N_, 256, 0, stream>>>(xf, ybuf, ln2s + l * D_, ln2b + l * D_, xf, xb);
  }

  // final LN + gate + logits
  k_ln<<<N_, 256, 0, stream>>>(xf, nullptr, lnOs, lnOb, xf, xb);
  gemm_bt<128, 64, 0, 0, 0><<<dim3(32, 8, 1), 256, 0, stream>>>(xb, 512, 0, 0, WgT, 512, 0, 0,
      (void*)ybuf, 512, 0, 0, bg, 0, 512, 512, 1);
  k_gate<<<(N_ * D_) / 256, 256, 0, stream>>>(xf, ybuf, organic, Wg + (size_t)512 * 512, xg);
  // logits: 4096x20000x512 -> 8-phase 256x256, NT streaming f32 stores
  gemm8<0, 0, 1><<<dim3(16, 79), 512, 0, stream>>>(xg, 512, WoutT, 512,
      (void*)out, 20000, bout, 512, 20000);
}

// Round 8
// 861.087 us; speedup vs baseline: 1.1083x; 1.0756x over previous
//
#include <hip/hip_runtime.h>
#include <hip/hip_bf16.h>

typedef float f32x4 __attribute__((ext_vector_type(4)));
typedef __bf16 bf16x8 __attribute__((ext_vector_type(8)));

#define DEV __device__ __forceinline__

constexpr int B_ = 8, S_ = 512, D_ = 512, H_ = 8, L_ = 4, DFF_ = 2048, NI_ = 20000, AD_ = 128, DK_ = 64;
constexpr int N_ = B_ * S_;            // 4096 tokens
constexpr int NOUT_PAD = 20096;        // 157 * 128

DEV void gload_lds16(const void* g, void* l) {
  __builtin_amdgcn_global_load_lds((const __attribute__((address_space(1))) unsigned int*)g,
                                   (__attribute__((address_space(3))) unsigned int*)l, 16, 0, 0);
}

// m204 bijective XCD-chunk swizzle
DEV int xcd_swizzle(int bid, int nwg) {
  int q = nwg >> 3, r = nwg & 7;
  int x = bid & 7, idx = bid >> 3;
  int base = (x < r) ? x * (q + 1) : r * (q + 1) + (x - r) * q;
  return base + idx;
}

// ---------------------------------------------------------------------------
// 2-phase bf16 GEMM, BK=64, T2 XOR-swizzled LDS (both-sides, rule #21):
//   LDS[row][c] = Global[row][c ^ (row&7)]   (16B chunks, 8 per row)
//   reader wants chunk k -> reads LDS[row][k ^ (row&7)]
// 4 waves (2x2), per-wave (BM/2)x(BN/2). Double-buffered, prefetch issued
// before compute, ONE __syncthreads per K-step (round-5 verified skeleton).
// EPI: 0=f32 store (+NT), 1=bf16 store, 2=Wf+PE (write xf f32 + xb bf16),
//      3=QKV wide (q,k rows; v transposed into vt), 4=gate (sigmoid*xf->bf16)
// ---------------------------------------------------------------------------
template<int BM, int BN, int EPI, int ACT, int NT>
__global__ __launch_bounds__(256)
void gemm2(const __hip_bfloat16* __restrict__ A, int lda,
           const __hip_bfloat16* __restrict__ Bm, int ldb,
           void* __restrict__ Cv, int ldc,
           const float* __restrict__ bias,
           const void* __restrict__ p1, const void* __restrict__ p2,
           const void* __restrict__ p3,
           int K, int Ncols)
{
  constexpr int BK = 64;
  constexpr int MI = BM / 32, NJ = BN / 32;
  constexpr int LA = BM * BK / 2048, LB = BN * BK / 2048;
  __shared__ __align__(16) unsigned short smA[2][BM * BK];
  __shared__ __align__(16) unsigned short smB[2][BN * BK];

  const int nwg = gridDim.x * gridDim.y;
  const int bid = blockIdx.y * gridDim.x + blockIdx.x;
  const int wgid = xcd_swizzle(bid, nwg);
  const int m0 = (wgid % gridDim.x) * BM, n0 = (wgid / gridDim.x) * BN;

  const int tid = threadIdx.x, wv = tid >> 6, lane = tid & 63;
  const int l15 = lane & 15, l4 = lane >> 4;
  const int wm = (wv >> 1) * (BM / 2), wn = (wv & 1) * (BN / 2);

  auto stage = [&](int buf, int k0) {
#pragma unroll
    for (int it = 0; it < LA; ++it) {
      int idx = it * 256 + tid, row = idx >> 3, c = idx & 7;
      int sc = c ^ (row & 7);
      gload_lds16((const void*)(A + (size_t)(m0 + row) * lda + k0 + sc * 8),
                  (void*)&smA[buf][(size_t)(it * 256 + wv * 64) * 8]);
    }
#pragma unroll
    for (int it = 0; it < LB; ++it) {
      int idx = it * 256 + tid, row = idx >> 3, c = idx & 7;
      int sc = c ^ (row & 7);
      gload_lds16((const void*)(Bm + (size_t)(n0 + row) * ldb + k0 + sc * 8),
                  (void*)&smB[buf][(size_t)(it * 256 + wv * 64) * 8]);
    }
  };

  f32x4 acc[MI][NJ];
#pragma unroll
  for (int i = 0; i < MI; ++i)
#pragma unroll
    for (int j = 0; j < NJ; ++j) acc[i][j] = f32x4{0.f, 0.f, 0.f, 0.f};

  const int nk = K / BK;
  stage(0, 0);
  __syncthreads();

  int cur = 0;
  for (int t = 0; t < nk; ++t) {
    if (t + 1 < nk) stage(cur ^ 1, (t + 1) * BK);   // prefetch issue (async)

    bf16x8 af[MI][2], bfr[NJ][2];
#pragma unroll
    for (int i = 0; i < MI; ++i)
#pragma unroll
      for (int kk = 0; kk < 2; ++kk) {
        int row = wm + i * 16 + l15;
        int ch = (kk * 4 + l4) ^ (row & 7);
        af[i][kk] = *reinterpret_cast<const bf16x8*>(&smA[cur][row * BK + ch * 8]);
      }
#pragma unroll
    for (int j = 0; j < NJ; ++j)
#pragma unroll
      for (int kk = 0; kk < 2; ++kk) {
        int row = wn + j * 16 + l15;
        int ch = (kk * 4 + l4) ^ (row & 7);
        bfr[j][kk] = *reinterpret_cast<const bf16x8*>(&smB[cur][row * BK + ch * 8]);
      }
    __builtin_amdgcn_s_setprio(1);
#pragma unroll
    for (int kk = 0; kk < 2; ++kk)
#pragma unroll
      for (int i = 0; i < MI; ++i)
#pragma unroll
        for (int j = 0; j < NJ; ++j)
          acc[i][j] = __builtin_amdgcn_mfma_f32_16x16x32_bf16(af[i][kk], bfr[j][kk], acc[i][j], 0, 0, 0);
    __builtin_amdgcn_s_setprio(0);
    __syncthreads();                     // prefetch landed for all waves
    cur ^= 1;
  }

  // epilogue: C/D layout col = lane&15, row = (lane>>4)*4 + r  [m89/m91 verified]
#pragma unroll
  for (int i = 0; i < MI; ++i) {
#pragma unroll
    for (int j = 0; j < NJ; ++j) {
#pragma unroll
      for (int r = 0; r < 4; ++r) {
        int row = m0 + wm + i * 16 + l4 * 4 + r;
        int col = n0 + wn + j * 16 + l15;
        if (col < Ncols) {
          float v = acc[i][j][r];
          if (bias) v += bias[col];
          if (ACT == 1) v = v > 0.f ? v : 0.f;
          if constexpr (EPI == 0) {
            float* dst = &((float*)Cv)[(size_t)row * ldc + col];
            if constexpr (NT) __builtin_nontemporal_store(v, dst);
            else *dst = v;
          } else if constexpr (EPI == 1) {
            ((__hip_bfloat16*)Cv)[(size_t)row * ldc + col] = __float2bfloat16(v);
          } else if constexpr (EPI == 2) {
            // Wf front-end: v = relu(..) already; add PE; write xf f32 + xb bf16
            v += ((const float*)p2)[(size_t)(row & 511) * 512 + col];
            ((float*)Cv)[(size_t)row * ldc + col] = v;
            ((__hip_bfloat16*)p1)[(size_t)row * ldc + col] = __float2bfloat16(v);
          } else if constexpr (EPI == 3) {
            // wide QKV: cols [0,1024) -> q,k rows; [1024,1536) -> v transposed
            if (col < 1024) {
              ((__hip_bfloat16*)Cv)[(size_t)(col >> 9) * N_ * 512 + (size_t)row * 512 + (col & 511)] =
                  __float2bfloat16(v);
            } else {
              int hd = col - 1024, b = row >> 9, s = row & 511;
              ((__hip_bfloat16*)p1)[((size_t)(b * 8 + (hd >> 6)) * 64 + (hd & 63)) * 512 + s] =
                  __float2bfloat16(v);
            }
          } else if constexpr (EPI == 4) {
            // gate: zz = v + organic[row]*wgl[col]; xg = bf16(xf*sigmoid(zz))
            float zz = v + ((const float*)p2)[row] * ((const float*)p3)[col];
            float sg = 1.f / (1.f + __expf(-zz));
            float xn = ((const float*)p1)[(size_t)row * 512 + col];
            ((__hip_bfloat16*)Cv)[(size_t)row * 512 + col] = __float2bfloat16(xn * sg);
          }
        }
      }
    }
  }
}

// ---------------------------------------------------------------------------
// Fused flash attention (verified round 5).
// ---------------------------------------------------------------------------
__global__ __launch_bounds__(256)
void k_flash(const __hip_bfloat16* __restrict__ q, const __hip_bfloat16* __restrict__ k,
             const __hip_bfloat16* __restrict__ vt, const float* __restrict__ mask,
             __hip_bfloat16* __restrict__ ctx)
{
  __shared__ __align__(16) unsigned short Ql[64 * 64];
  __shared__ __align__(16) unsigned short Kl[2][64 * 64];
  __shared__ __align__(16) unsigned short Vl[2][64 * 64];
  __shared__ __align__(16) unsigned short Pl[4][16 * 64];

  const int qt = blockIdx.x, bh = blockIdx.y;
  const int b = bh >> 3, h = bh & 7;
  const int tid = threadIdx.x, wv = tid >> 6, lane = tid & 63;
  const int l15 = lane & 15, l4 = lane >> 4;
  const int q0 = qt * 64;

  const __hip_bfloat16* Qg = q + ((size_t)(b * 512 + q0) * 512) + h * 64;
  const __hip_bfloat16* Kg = k + ((size_t)(b * 512) * 512) + h * 64;
  const __hip_bfloat16* Vg = vt + ((size_t)bh * 64) * 512;
  const float* mk = mask + b * 512;

  auto stageQ = [&]() {
#pragma unroll
    for (int it = 0; it < 2; ++it) {
      int idx = it * 256 + wv * 64 + lane;
      int row = idx >> 3, c = idx & 7;
      gload_lds16((const void*)(Qg + (size_t)row * 512 + (c ^ (row & 7)) * 8),
                  (void*)&Ql[(it * 256 + wv * 64) * 8]);
    }
  };
  auto stageKV = [&](int buf, int kv0) {
#pragma unroll
    for (int it = 0; it < 2; ++it) {
      int idx = it * 256 + wv * 64 + lane;
      int row = idx >> 3, c = idx & 7;
      gload_lds16((const void*)(Kg + (size_t)(kv0 + row) * 512 + (c ^ (row & 7)) * 8),
                  (void*)&Kl[buf][(it * 256 + wv * 64) * 8]);
    }
#pragma unroll
    for (int it = 0; it < 2; ++it) {
      int idx = it * 256 + wv * 64 + lane;
      int row = idx >> 3, c = idx & 7;
      gload_lds16((const void*)(Vg + (size_t)row * 512 + kv0 + (c ^ (row & 7)) * 8),
                  (void*)&Vl[buf][(it * 256 + wv * 64) * 8]);
    }
  };

  stageQ();
  stageKV(0, 0);
  __syncthreads();

  bf16x8 aq[2];
#pragma unroll
  for (int kk = 0; kk < 2; ++kk) {
    int row = wv * 16 + l15;
    aq[kk] = *reinterpret_cast<const bf16x8*>(
        &Ql[row * 64 + (((kk * 4 + l4) ^ (row & 7)) * 8)]);
  }

  f32x4 accO[4];
  float mrun[4], lrun[4];
#pragma unroll
  for (int j = 0; j < 4; ++j) accO[j] = f32x4{0.f, 0.f, 0.f, 0.f};
#pragma unroll
  for (int r = 0; r < 4; ++r) { mrun[r] = -3e38f; lrun[r] = 0.f; }

  int cur = 0;
  for (int t = 0; t < 8; ++t) {
    if (t + 1 < 8) stageKV(cur ^ 1, (t + 1) * 64);
    const int kv0 = t * 64;

    f32x4 s[4];
#pragma unroll
    for (int j = 0; j < 4; ++j) s[j] = f32x4{0.f, 0.f, 0.f, 0.f};
#pragma unroll
    for (int kk = 0; kk < 2; ++kk) {
#pragma unroll
      for (int j = 0; j < 4; ++j) {
        int row = j * 16 + l15;
        bf16x8 bk = *reinterpret_cast<const bf16x8*>(
            &Kl[cur][row * 64 + (((kk * 4 + l4) ^ (row & 7)) * 8)]);
        s[j] = __builtin_amdgcn_mfma_f32_16x16x32_bf16(aq[kk], bk, s[j], 0, 0, 0);
      }
    }

#pragma unroll
    for (int j = 0; j < 4; ++j) {
      float mval = mk[kv0 + j * 16 + l15];
#pragma unroll
      for (int r = 0; r < 4; ++r)
        s[j][r] = (mval == 0.f) ? -1e30f : s[j][r];
    }

    float alpha[4];
#pragma unroll
    for (int r = 0; r < 4; ++r) {
      float v = fmaxf(fmaxf(s[0][r], s[1][r]), fmaxf(s[2][r], s[3][r]));
      v = fmaxf(v, __shfl_xor(v, 1));
      v = fmaxf(v, __shfl_xor(v, 2));
      v = fmaxf(v, __shfl_xor(v, 4));
      v = fmaxf(v, __shfl_xor(v, 8));
      float mn = fmaxf(mrun[r], v);
      alpha[r] = __expf(mrun[r] - mn);
      mrun[r] = mn;
    }
    float rs[4] = {0.f, 0.f, 0.f, 0.f};
#pragma unroll
    for (int j = 0; j < 4; ++j)
#pragma unroll
      for (int r = 0; r < 4; ++r) {
        float p = __expf(s[j][r] - mrun[r]);
        s[j][r] = p;
        rs[r] += p;
      }
#pragma unroll
    for (int r = 0; r < 4; ++r) {
      float v = rs[r];
      v += __shfl_xor(v, 1); v += __shfl_xor(v, 2);
      v += __shfl_xor(v, 4); v += __shfl_xor(v, 8);
      lrun[r] = lrun[r] * alpha[r] + v;
#pragma unroll
      for (int j = 0; j < 4; ++j) accO[j][r] *= alpha[r];
    }

#pragma unroll
    for (int j = 0; j < 4; ++j)
#pragma unroll
      for (int r = 0; r < 4; ++r) {
        int qrow = l4 * 4 + r, key = j * 16 + l15;
        __hip_bfloat16 hb = __float2bfloat16(s[j][r]);
        Pl[wv][qrow * 64 + (((key >> 3) ^ (qrow & 7)) * 8) + (key & 7)] =
            *reinterpret_cast<unsigned short*>(&hb);
      }

#pragma unroll
    for (int kc = 0; kc < 2; ++kc) {
      bf16x8 ap = *reinterpret_cast<const bf16x8*>(
          &Pl[wv][l15 * 64 + (((kc * 4 + l4) ^ (l15 & 7)) * 8)]);
#pragma unroll
      for (int j = 0; j < 4; ++j) {
        int row = j * 16 + l15;
        bf16x8 bv2 = *reinterpret_cast<const bf16x8*>(
            &Vl[cur][row * 64 + (((kc * 4 + l4) ^ (row & 7)) * 8)]);
        accO[j] = __builtin_amdgcn_mfma_f32_16x16x32_bf16(ap, bv2, accO[j], 0, 0, 0);
      }
    }
    __syncthreads();
    cur ^= 1;
  }

#pragma unroll
  for (int r = 0; r < 4; ++r) {
    float inv = lrun[r] > 0.f ? 1.f / lrun[r] : 0.f;
#pragma unroll
    for (int j = 0; j < 4; ++j) {
      int row = q0 + wv * 16 + l4 * 4 + r;
      int col = h * 64 + j * 16 + l15;
      ctx[(size_t)(b * 512 + row) * 512 + col] = __float2bfloat16(accO[j][r] * inv);
    }
  }
}

// ---------------------------------------------------------------------------
__global__ void k_transpose(const float* __restrict__ in, __hip_bfloat16* __restrict__ out,
                            int K, int N, long inBatch, long outBatch, float scale)
{
  __shared__ float tile[32][33];
  int z = blockIdx.z;
  const float* ip = in + (long)z * inBatch;
  __hip_bfloat16* op = out + (long)z * outBatch;
  int n0 = blockIdx.x * 32, k0 = blockIdx.y * 32;
  int tx = threadIdx.x, ty = threadIdx.y;
#pragma unroll
  for (int r = 0; r < 4; ++r) {
    int k = k0 + ty + r * 8, n = n0 + tx;
    if (k < K && n < N) tile[ty + r * 8][tx] = ip[(size_t)k * N + n];
  }
  __syncthreads();
#pragma unroll
  for (int r = 0; r < 4; ++r) {
    int n = n0 + ty + r * 8, k = k0 + tx;
    if (n < N && k < K) op[(size_t)n * K + k] = __float2bfloat16(tile[tx][ty + r * 8] * scale);
  }
}

__global__ void k_cvt(const float* __restrict__ in, __hip_bfloat16* __restrict__ out) {
  int i = blockIdx.x * 256 + threadIdx.x;
  out[i] = __float2bfloat16(in[i]);
}

__global__ void k_packbias(const float* __restrict__ bq, const float* __restrict__ bk,
                           const float* __restrict__ bv, float* __restrict__ out) {
  int i = blockIdx.x * 256 + threadIdx.x;   // L*3*512
  int d = i & 511, t = (i >> 9) % 3, l = i / (3 * 512);
  const float* src = (t == 0) ? bq : (t == 1) ? bk : bv;
  out[i] = src[l * 512 + d] * (t == 0 ? 0.125f : 1.f);
}

__global__ void k_gather(const int* __restrict__ ids, const float* __restrict__ tbl,
                         __hip_bfloat16* __restrict__ cat) {
  int n = blockIdx.x, t = threadIdx.x;
  int id = ids[n];
  const float* src = tbl + (size_t)id * 512;
  size_t dst = (size_t)n * 1024;
  float a0 = (id == 0) ? 0.f : src[t];
  float a1 = (id == 0) ? 0.f : src[t + 256];
  cat[dst + t] = __float2bfloat16(a0);
  cat[dst + t + 256] = __float2bfloat16(a1);
}

__global__ void k_ln(const float* __restrict__ x, const float* __restrict__ y,
                     const float* __restrict__ gam, const float* __restrict__ bet,
                     float* __restrict__ xout, __hip_bfloat16* __restrict__ xb) {
  int row = blockIdx.x, t = threadIdx.x;
  size_t base = (size_t)row * 512;
  float v0 = x[base + t], v1 = x[base + t + 256];
  if (y) { v0 += y[base + t]; v1 += y[base + t + 256]; }
  __shared__ float sm[4];
  float s = v0 + v1;
  for (int o = 32; o; o >>= 1) s += __shfl_xor(s, o);
  if ((t & 63) == 0) sm[t >> 6] = s;
  __syncthreads();
  float mean = (sm[0] + sm[1] + sm[2] + sm[3]) * (1.f / 512.f);
  __syncthreads();
  float d0 = v0 - mean, d1 = v1 - mean;
  float qq = d0 * d0 + d1 * d1;
  for (int o = 32; o; o >>= 1) qq += __shfl_xor(qq, o);
  if ((t & 63) == 0) sm[t >> 6] = qq;
  __syncthreads();
  float var = (sm[0] + sm[1] + sm[2] + sm[3]) * (1.f / 512.f);
  float rs = rsqrtf(var + 1e-5f);
  float o0 = d0 * rs * gam[t] + bet[t];
  float o1 = d1 * rs * gam[t + 256] + bet[t + 256];
  xout[base + t] = o0;
  xout[base + t + 256] = o1;
  xb[base + t] = __float2bfloat16(o0);
  xb[base + t + 256] = __float2bfloat16(o1);
}

// ---------------------------------------------------------------------------
extern "C" void kernel_launch(void* const* d_in, const int* in_sizes, int n_in,
                              void* d_out, int out_size, void* d_ws, size_t ws_size,
                              hipStream_t stream) {
  typedef __hip_bfloat16 bf;
  const int*   item_ids = (const int*)  d_in[0];
  const float* audio    = (const float*)d_in[1];
  const float* organic  = (const float*)d_in[2];
  const float* mask     = (const float*)d_in[3];
  const float* emb      = (const float*)d_in[4];
  const float* pe       = (const float*)d_in[5];
  const float* Wa1 = (const float*)d_in[6],  *ba1 = (const float*)d_in[7];
  const float* Wa2 = (const float*)d_in[8],  *ba2 = (const float*)d_in[9];
  const float* Wf  = (const float*)d_in[10], *bfb = (const float*)d_in[11];
  const float* Wq  = (const float*)d_in[12], *bq  = (const float*)d_in[13];
  const float* Wk  = (const float*)d_in[14], *bk  = (const float*)d_in[15];
  const float* Wv  = (const float*)d_in[16], *bv  = (const float*)d_in[17];
  const float* Wo  = (const float*)d_in[18], *bo  = (const float*)d_in[19];
  const float* ln1s = (const float*)d_in[22], *ln1b = (const float*)d_in[23];
  const float* ln2s = (const float*)d_in[24], *ln2b = (const float*)d_in[25];
  const float* Wff1 = (const float*)d_in[26], *bff1 = (const float*)d_in[27];
  const float* Wff2 = (const float*)d_in[28], *bff2 = (const float*)d_in[29];
  const float* lnOs = (const float*)d_in[30], *lnOb = (const float*)d_in[31];
  const float* Wg   = (const float*)d_in[32], *bg   = (const float*)d_in[33];
  const float* Wout = (const float*)d_in[34], *bout = (const float*)d_in[35];
  float* out = (float*)d_out;

  char* ws = (char*)d_ws;
  size_t off = 0;
  auto alloc = [&](size_t bytes) -> char* {
    char* p = ws + off;
    off = (off + bytes + 255) & ~(size_t)255;
    return p;
  };
  bf* Wa1T = (bf*)alloc((size_t)512 * 128 * 2);
  bf* Wa2T = (bf*)alloc((size_t)512 * 512 * 2);
  bf* WfT  = (bf*)alloc((size_t)512 * 1024 * 2);
  bf* WqkvT = (bf*)alloc((size_t)L_ * 3 * D_ * D_ * 2);   // [L][3*D][D]
  bf* WoT  = (bf*)alloc((size_t)L_ * D_ * D_ * 2);
  bf* Wff1T = (bf*)alloc((size_t)L_ * DFF_ * D_ * 2);
  bf* Wff2T = (bf*)alloc((size_t)L_ * D_ * DFF_ * 2);
  bf* WgT   = (bf*)alloc((size_t)512 * 512 * 2);
  bf* WoutT = (bf*)alloc((size_t)NOUT_PAD * 512 * 2);
  float* bqkv = (float*)alloc((size_t)L_ * 3 * 512 * 4);
  bf* ab    = (bf*)alloc((size_t)N_ * AD_ * 2);
  bf* cat   = (bf*)alloc((size_t)N_ * 1024 * 2);
  bf* ah    = (bf*)alloc((size_t)N_ * 512 * 2);
  float* xf = (float*)alloc((size_t)N_ * 512 * 4);
  bf* xb    = (bf*)alloc((size_t)N_ * 512 * 2);
  bf* qkv   = (bf*)alloc((size_t)3 * N_ * 512 * 2);       // [3][N][D] (v slot unused)
  bf* vt    = (bf*)alloc((size_t)B_ * H_ * DK_ * S_ * 2);
  bf* ctxb  = (bf*)alloc((size_t)N_ * 512 * 2);
  float* ybuf = (float*)alloc((size_t)N_ * 512 * 4);
  bf* ff1b  = (bf*)alloc((size_t)N_ * DFF_ * 2);
  bf* xg    = (bf*)alloc((size_t)N_ * 512 * 2);
  if (off > ws_size) return;  // loud failure (output stays poisoned)

  bf* qb = qkv;
  bf* kb = qkv + (size_t)N_ * 512;

  dim3 tb(32, 8);
  // weight transposes -> bf16, K-major (Wq scaled by 1/8: attention scale folded)
  k_transpose<<<dim3(16, 4, 1),  tb, 0, stream>>>(Wa1, Wa1T, 128, 512, 0, 0, 1.f);
  k_transpose<<<dim3(16, 16, 1), tb, 0, stream>>>(Wa2, Wa2T, 512, 512, 0, 0, 1.f);
  k_transpose<<<dim3(16, 32, 1), tb, 0, stream>>>(Wf, WfT, 1024, 512, 0, 0, 1.f);
  k_transpose<<<dim3(16, 16, L_), tb, 0, stream>>>(Wq, WqkvT, 512, 512,
      (long)D_ * D_, (long)3 * D_ * D_, 0.125f);
  k_transpose<<<dim3(16, 16, L_), tb, 0, stream>>>(Wk, WqkvT + (size_t)D_ * D_, 512, 512,
      (long)D_ * D_, (long)3 * D_ * D_, 1.f);
  k_transpose<<<dim3(16, 16, L_), tb, 0, stream>>>(Wv, WqkvT + (size_t)2 * D_ * D_, 512, 512,
      (long)D_ * D_, (long)3 * D_ * D_, 1.f);
  k_transpose<<<dim3(16, 16, L_), tb, 0, stream>>>(Wo, WoT, 512, 512, (long)D_ * D_, (long)D_ * D_, 1.f);
  k_transpose<<<dim3(64, 16, L_), tb, 0, stream>>>(Wff1, Wff1T, 512, 2048, (long)D_ * DFF_, (long)D_ * DFF_, 1.f);
  k_transpose<<<dim3(16, 64, L_), tb, 0, stream>>>(Wff2, Wff2T, 2048, 512, (long)DFF_ * D_, (long)DFF_ * D_, 1.f);
  k_transpose<<<dim3(16, 16, 1), tb, 0, stream>>>(Wg, WgT, 512, 512, 0, 0, 1.f);
  k_transpose<<<dim3(625, 16, 1), tb, 0, stream>>>(Wout, WoutT, 512, 20000, 0, 0, 1.f);
  k_packbias<<<(L_ * 3 * 512) / 256, 256, 0, stream>>>(bq, bk, bv, bqkv);

  // front-end
  k_cvt<<<(N_ * AD_) / 256, 256, 0, stream>>>(audio, ab);
  k_gather<<<N_, 256, 0, stream>>>(item_ids, emb, cat);
  gemm2<128, 64, 1, 1, 0><<<dim3(32, 8), 256, 0, stream>>>(ab, 128, Wa1T, 128,
      (void*)ah, 512, ba1, nullptr, nullptr, nullptr, 128, 512);
  gemm2<128, 64, 1, 0, 0><<<dim3(32, 8), 256, 0, stream>>>(ah, 512, Wa2T, 512,
      (void*)(cat + 512), 1024, ba2, nullptr, nullptr, nullptr, 512, 512);
  // Wf + fused PE-add: writes xf (f32) + xb (bf16)
  gemm2<128, 64, 2, 1, 0><<<dim3(32, 8), 256, 0, stream>>>(cat, 1024, WfT, 1024,
      (void*)xf, 512, bfb, (void*)xb, (const void*)pe, nullptr, 1024, 512);

  // layers
  for (int l = 0; l < L_; ++l) {
    // wide QKV (N=1536): q,k rows + v transposed into vt
    gemm2<128, 64, 3, 0, 0><<<dim3(32, 24), 256, 0, stream>>>(xb, 512,
        WqkvT + (size_t)l * 3 * D_ * D_, 512, (void*)qkv, 512,
        bqkv + (size_t)l * 3 * 512, (void*)vt, nullptr, nullptr, 512, 1536);
    k_flash<<<dim3(8, B_ * H_), 256, 0, stream>>>(qb, kb, vt, mask, ctxb);
    gemm2<128, 64, 0, 0, 0><<<dim3(32, 8), 256, 0, stream>>>(ctxb, 512,
        WoT + (size_t)l * D_ * D_, 512, (void*)ybuf, 512, bo + l * D_,
        nullptr, nullptr, nullptr, 512, 512);
    k_ln<<<N_, 256, 0, stream>>>(xf, ybuf, ln1s + l * D_, ln1b + l * D_, xf, xb);
    gemm2<128, 128, 1, 1, 0><<<dim3(32, 16), 256, 0, stream>>>(xb, 512,
        Wff1T + (size_t)l * DFF_ * D_, 512, (void*)ff1b, 2048, bff1 + l * DFF_,
        nullptr, nullptr, nullptr, 512, 2048);
    gemm2<128, 64, 0, 0, 0><<<dim3(32, 8), 256, 0, stream>>>(ff1b, 2048,
        Wff2T + (size_t)l * D_ * DFF_, 2048, (void*)ybuf, 512, bff2 + l * D_,
        nullptr, nullptr, nullptr, 2048, 512);
    k_ln<<<N_, 256, 0, stream>>>(xf, ybuf, ln2s + l * D_, ln2b + l * D_, xf, xb);
  }

  // final LN + gate(fused) + logits
  k_ln<<<N_, 256, 0, stream>>>(xf, nullptr, lnOs, lnOb, xf, xb);
  gemm2<128, 64, 4, 0, 0><<<dim3(32, 8), 256, 0, stream>>>(xb, 512, WgT, 512,
      (void*)xg, 512, bg, (const void*)xf, (const void*)organic,
      (const void*)(Wg + (size_t)512 * 512), 512, 512);
  // logits: 4096x20000x512, 128x128, NT streaming f32 stores
  gemm2<128, 128, 0, 0, 1><<<dim3(32, 157), 256, 0, stream>>>(xg, 512, WoutT, 512,
      (void*)out, 20000, bout, nullptr, nullptr, nullptr, 512, 20000);
}